// Round 6
// baseline (127.959 us; speedup 1.0000x reference)
//
#include <hip/hip_runtime.h>

// Problem constants (match reference)
constexpr int B = 128;
constexpr int N = 16384;
constexpr int H = 512;
constexpr int W = 512;
constexpr int HW = H * W;                        // 262144
constexpr long long TOT = (long long)B * HW;     // 33554432 pixels

constexpr int TROWS = 16;                        // rows per tile (32 KiB LDS)
constexpr int NTILES = H / TROWS;                // 32 tiles per frame
constexpr int NBUCKETS = B * NTILES;             // 4096
constexpr int BLK_PER_FRAME = 8;                 // bin blocks per frame
constexpr int BIN_BLOCKS = B * BLK_PER_FRAME;    // 1024 (2048 pts/block)
constexpr int KSEG = 128;                        // slots per (binblk, tile) segment
                                                 // mean occupancy ~68, 7 sigma headroom
// bucket layout: [frame][tile][binblk][KSEG] float4 -> per (frame,tile) a
// CONTIGUOUS 8*KSEG = 1024 float4 = 16 KiB block. Total 64 MiB, every slot
// written every call (points or zero-pads) -> no counters, no memset.

// ---------------------------------------------------------------------------
// Kernel 1: bin 2048 points of one frame into 32 tile-segments (this block's
// private slots). LDS slot counters only; zero-pad segment tails.
// ---------------------------------------------------------------------------
__global__ void __launch_bounds__(512) k_bin(const float4* __restrict__ pts,
                                             float4* __restrict__ buckets) {
    __shared__ unsigned int lcnt[NTILES];
    int bid = blockIdx.x;
    int frame = bid >> 3;                        // BLK_PER_FRAME = 8
    int blk = bid & 7;
    int g = bid * 512 + threadIdx.x;             // group of 4 points

    if (threadIdx.x < NTILES) lcnt[threadIdx.x] = 0;
    __syncthreads();

    float4 a = pts[g * 3 + 0];   // x0 y0 i0 x1
    float4 b = pts[g * 3 + 1];   // y1 i1 x2 y2
    float4 c = pts[g * 3 + 2];   // i2 x3 y3 i3

    float xs[4] = {a.x, a.w, b.z, c.y};
    float ys[4] = {a.y, b.x, b.w, c.z};
    float is[4] = {a.z, b.y, c.x, c.w};

    // segment base for tile t: ((frame*32 + t)*8 + blk) * KSEG
    size_t fbase = ((size_t)frame * NTILES * BLK_PER_FRAME + blk) * KSEG;
#pragma unroll
    for (int k = 0; k < 4; ++k) {
        float x = fminf(fmaxf(xs[k], 0.0f), (float)(W - 1));
        float y = fminf(fmaxf(ys[k], 0.0f), (float)(H - 1));
        int y0 = (int)floorf(y);
        int y1 = min(y0 + 1, H - 1);
        int t0 = y0 >> 4;                        // TROWS = 16
        int t1 = y1 >> 4;
        float4 rec = make_float4(x, y, is[k], 0.0f);
        unsigned s0 = atomicAdd(&lcnt[t0], 1u);
        if (s0 < (unsigned)KSEG)
            buckets[fbase + (size_t)t0 * (BLK_PER_FRAME * KSEG) + s0] = rec;
        if (t1 != t0) {
            unsigned s1 = atomicAdd(&lcnt[t1], 1u);
            if (s1 < (unsigned)KSEG)
                buckets[fbase + (size_t)t1 * (BLK_PER_FRAME * KSEG) + s1] = rec;
        }
    }
    __syncthreads();

    // zero-pad segment tails: 32 teams of 16 lanes, consecutive slots coalesced
    int team = threadIdx.x >> 4;
    int lane = threadIdx.x & 15;
    unsigned start = min(lcnt[team], (unsigned)KSEG);
    float4* seg = buckets + fbase + (size_t)team * (BLK_PER_FRAME * KSEG);
    float4 z = make_float4(0.f, 0.f, 0.f, 0.f);
    for (int s = (int)start + lane; s < KSEG; s += 16)
        seg[s] = z;
}

// ---------------------------------------------------------------------------
// Kernel 2: per-(frame,tile) block. All global loads issued up front
// (2 point-float4 + 4 target-float4 per thread, fixed contiguous addresses),
// zero LDS, barrier (drains loads), splat exactly 2 points/thread via
// ds_add_f32, barrier, squared-diff from registers.
// ---------------------------------------------------------------------------
__device__ __forceinline__ void lds_add(float* p, float v) {
    __hip_atomic_fetch_add(p, v, __ATOMIC_RELAXED, __HIP_MEMORY_SCOPE_WORKGROUP);
}

__device__ __forceinline__ void splat(float4 p, float* __restrict__ tile, int r0) {
    float x = p.x, y = p.y, inten = p.z;
    float x0f = floorf(x), y0f = floorf(y);
    float fx = x - x0f, fy = y - y0f;
    int x0 = (int)x0f, y0 = (int)y0f;
    int x1 = min(x0 + 1, W - 1);
    int y1 = min(y0 + 1, H - 1);
    int ra = y0 - r0;
    int rb = y1 - r0;
    float w00 = inten * (1.0f - fx) * (1.0f - fy);
    float w01 = inten * fx * (1.0f - fy);
    float w10 = inten * (1.0f - fx) * fy;
    float w11 = inten * fx * fy;
    if ((unsigned)ra < (unsigned)TROWS) {
        lds_add(&tile[ra * W + x0], w00);
        lds_add(&tile[ra * W + x1], w01);
    }
    if ((unsigned)rb < (unsigned)TROWS) {
        lds_add(&tile[rb * W + x0], w10);
        lds_add(&tile[rb * W + x1], w11);
    }
}

__global__ void __launch_bounds__(512) k_tile(const float4* __restrict__ buckets,
                                              const float* __restrict__ tgt,
                                              double* __restrict__ partials) {
    __shared__ float tile[TROWS * W];            // 32 KiB
    __shared__ double sacc[8];
    int bid = blockIdx.x;                        // == frame*32 + t
    int frame = bid >> 5;
    int t = bid & (NTILES - 1);
    int r0 = t * TROWS;

    // ---- issue ALL global loads immediately (6 float4 in flight) ----
    const float4* bp = buckets + (size_t)bid * (BLK_PER_FRAME * KSEG);
    float4 p0 = bp[threadIdx.x];
    float4 p1 = bp[threadIdx.x + 512];
    const float4* tg = (const float4*)(tgt + (size_t)frame * HW + (size_t)r0 * W);
    float4 tv0 = tg[threadIdx.x];
    float4 tv1 = tg[threadIdx.x + 512];
    float4 tv2 = tg[threadIdx.x + 1024];
    float4 tv3 = tg[threadIdx.x + 1536];

    // ---- zero LDS tile while loads fly ----
    float4* t4 = (float4*)tile;
    float4 z = make_float4(0.f, 0.f, 0.f, 0.f);
#pragma unroll
    for (int k = 0; k < 4; ++k)
        t4[threadIdx.x + k * 512] = z;
    __syncthreads();                             // drains vmcnt too

    // ---- splat exactly 2 slots per thread (pads have inten=0) ----
    splat(p0, tile, r0);
    splat(p1, tile, r0);
    __syncthreads();

    // ---- squared diff, targets already in registers ----
    double acc = 0.0;
    {
        float4 sv = t4[threadIdx.x];
        float d0 = sv.x - tv0.x, d1 = sv.y - tv0.y, d2 = sv.z - tv0.z, d3 = sv.w - tv0.w;
        acc += (double)(d0 * d0 + d1 * d1) + (double)(d2 * d2 + d3 * d3);
        sv = t4[threadIdx.x + 512];
        d0 = sv.x - tv1.x; d1 = sv.y - tv1.y; d2 = sv.z - tv1.z; d3 = sv.w - tv1.w;
        acc += (double)(d0 * d0 + d1 * d1) + (double)(d2 * d2 + d3 * d3);
        sv = t4[threadIdx.x + 1024];
        d0 = sv.x - tv2.x; d1 = sv.y - tv2.y; d2 = sv.z - tv2.z; d3 = sv.w - tv2.w;
        acc += (double)(d0 * d0 + d1 * d1) + (double)(d2 * d2 + d3 * d3);
        sv = t4[threadIdx.x + 1536];
        d0 = sv.x - tv3.x; d1 = sv.y - tv3.y; d2 = sv.z - tv3.z; d3 = sv.w - tv3.w;
        acc += (double)(d0 * d0 + d1 * d1) + (double)(d2 * d2 + d3 * d3);
    }

    for (int off = 32; off > 0; off >>= 1)
        acc += __shfl_down(acc, off, 64);
    int lane = threadIdx.x & 63;
    int wave = threadIdx.x >> 6;
    if (lane == 0) sacc[wave] = acc;
    __syncthreads();
    if (threadIdx.x == 0) {
        double s = 0.0;
#pragma unroll
        for (int wv = 0; wv < 8; ++wv) s += sacc[wv];
        partials[bid] = s;
    }
}

// ---------------------------------------------------------------------------
// Kernel 3: final reduce of NBUCKETS partials -> mean -> d_out[0]
// ---------------------------------------------------------------------------
__global__ void __launch_bounds__(512) k_final(const double* __restrict__ partials,
                                               float* __restrict__ out) {
    double acc = 0.0;
    for (int i = threadIdx.x; i < NBUCKETS; i += 512)
        acc += partials[i];
    for (int off = 32; off > 0; off >>= 1)
        acc += __shfl_down(acc, off, 64);
    __shared__ double sacc[8];
    int lane = threadIdx.x & 63;
    int wave = threadIdx.x >> 6;
    if (lane == 0) sacc[wave] = acc;
    __syncthreads();
    if (threadIdx.x == 0) {
        double s = 0.0;
#pragma unroll
        for (int wv = 0; wv < 8; ++wv) s += sacc[wv];
        out[0] = (float)(s / (double)TOT);
    }
}

// ---------------------------------------------------------------------------
extern "C" void kernel_launch(void* const* d_in, const int* in_sizes, int n_in,
                              void* d_out, int out_size, void* d_ws, size_t ws_size,
                              hipStream_t stream) {
    const float* pts = (const float*)d_in[0];     // [B, N, 3]
    const float* tgt = (const float*)d_in[1];     // [B, H, W]
    float* out = (float*)d_out;

    // ws layout: [ partials 32KB | pad to 64KB | buckets 64MiB ]
    double* partials = (double*)d_ws;
    float4* buckets = (float4*)((char*)d_ws + 65536);

    k_bin<<<BIN_BLOCKS, 512, 0, stream>>>((const float4*)pts, buckets);
    k_tile<<<NBUCKETS, 512, 0, stream>>>(buckets, tgt, partials);
    k_final<<<1, 512, 0, stream>>>(partials, out);
}

// Round 7
// 104.546 us; speedup vs baseline: 1.2239x; 1.2239x over previous
//
#include <hip/hip_runtime.h>

// Problem constants (match reference)
constexpr int B = 128;
constexpr int N = 16384;
constexpr int H = 512;
constexpr int W = 512;
constexpr int HW = H * W;                        // 262144
constexpr long long TOT = (long long)B * HW;     // 33554432 pixels
constexpr int TOT4 = (int)(TOT / 4);             // 8388608 float4

constexpr int TROWS = 16;                        // rows per tile
constexpr int NTILES = H / TROWS;                // 32 tiles per frame
constexpr int NBUCKETS = B * NTILES;             // 4096
constexpr int CAP = 1024;                        // slots per bucket (mean ~544)
constexpr int NGROUPS = B * N / 4;               // 524288 groups of 4 points
constexpr int BIN_BLOCKS = NGROUPS / 512;        // 1024
constexpr int TPITCH = 520;                      // padded pitch: 4 adds -> 4 banks
constexpr int TILE_WORDS = TROWS * TPITCH;       // 8320 floats = 33280 B

__device__ __forceinline__ void lds_add(float* p, float v) {
    __hip_atomic_fetch_add(p, v, __ATOMIC_RELAXED, __HIP_MEMORY_SCOPE_WORKGROUP);
}

// ---------------------------------------------------------------------------
// Kernel 1: bin points by (frame, row-tile) [LDS slot aggregation, proven
// ~5us in r4] + Sum(tgt^2) full-BW grid-stride stream.
// ---------------------------------------------------------------------------
__global__ void __launch_bounds__(512) k_bin(const float4* __restrict__ pts,
                                             float4* __restrict__ buckets,
                                             unsigned int* __restrict__ cnt,
                                             const float4* __restrict__ tgt4,
                                             double* __restrict__ pbin) {
    __shared__ unsigned int lcnt[NTILES];
    __shared__ unsigned int lbase[NTILES];
    __shared__ double sacc[8];

    int tid = blockIdx.x * 512 + threadIdx.x;    // one group of 4 points
    int frame = tid >> 12;                       // 4096 groups per frame
    int fb = frame * NTILES;

    if (threadIdx.x < NTILES) lcnt[threadIdx.x] = 0;
    __syncthreads();

    float4 a = pts[tid * 3 + 0];   // x0 y0 i0 x1
    float4 b = pts[tid * 3 + 1];   // y1 i1 x2 y2
    float4 c = pts[tid * 3 + 2];   // i2 x3 y3 i3

    float xs[4] = {a.x, a.w, b.z, c.y};
    float ys[4] = {a.y, b.x, b.w, c.z};
    float is[4] = {a.z, b.y, c.x, c.w};

    int tb0[4], sl0[4], tb1[4], sl1[4];
#pragma unroll
    for (int k = 0; k < 4; ++k) {
        float x = fminf(fmaxf(xs[k], 0.0f), (float)(W - 1));
        float y = fminf(fmaxf(ys[k], 0.0f), (float)(H - 1));
        xs[k] = x; ys[k] = y;
        int y0 = (int)floorf(y);
        int y1 = min(y0 + 1, H - 1);
        int t0 = y0 >> 4;                         // TROWS = 16
        int t1 = y1 >> 4;
        tb0[k] = t0;
        sl0[k] = (int)atomicAdd(&lcnt[t0], 1u);
        if (t1 != t0) {
            tb1[k] = t1;
            sl1[k] = (int)atomicAdd(&lcnt[t1], 1u);
        } else {
            tb1[k] = -1; sl1[k] = 0;
        }
    }
    __syncthreads();

    if (threadIdx.x < NTILES)
        lbase[threadIdx.x] = atomicAdd(&cnt[fb + threadIdx.x], lcnt[threadIdx.x]);
    __syncthreads();

#pragma unroll
    for (int k = 0; k < 4; ++k) {
        float4 rec = make_float4(xs[k], ys[k], is[k], 0.0f);
        unsigned s0 = lbase[tb0[k]] + (unsigned)sl0[k];
        if (s0 < (unsigned)CAP)
            buckets[(size_t)(fb + tb0[k]) * CAP + s0] = rec;
        if (tb1[k] >= 0) {
            unsigned s1 = lbase[tb1[k]] + (unsigned)sl1[k];
            if (s1 < (unsigned)CAP)
                buckets[(size_t)(fb + tb1[k]) * CAP + s1] = rec;
        }
    }

    // ---- Sum(tgt^2): full-BW stream, 16 float4 per thread ----
    double acc = 0.0;
    for (int i = tid; i < TOT4; i += NGROUPS) {
        float4 t = tgt4[i];
        acc += (double)(t.x * t.x + t.y * t.y) + (double)(t.z * t.z + t.w * t.w);
    }
    for (int off = 32; off > 0; off >>= 1)
        acc += __shfl_down(acc, off, 64);
    int lane = threadIdx.x & 63;
    int wave = threadIdx.x >> 6;
    if (lane == 0) sacc[wave] = acc;
    __syncthreads();
    if (threadIdx.x == 0) {
        double s = 0.0;
#pragma unroll
        for (int wv = 0; wv < 8; ++wv) s += sacc[wv];
        pbin[blockIdx.x] = s;
    }
}

// ---------------------------------------------------------------------------
// Kernel 2: per-(frame,tile) block. Splat bucket points into bank-padded
// LDS tile (ds_add) + fused per-point 4-pixel target gather for the cross
// term. Emits  Sum(img^2) - 2*Sum(img*tgt)  for its tile.
// ---------------------------------------------------------------------------
__global__ void __launch_bounds__(512) k_tile(const float4* __restrict__ buckets,
                                              const unsigned int* __restrict__ cnt,
                                              const float* __restrict__ tgt,
                                              double* __restrict__ ptile) {
    __shared__ float tile[TILE_WORDS];           // [16][520] fp32, 33280 B
    __shared__ double sacc[8];
    int bid = blockIdx.x;
    int frame = bid >> 5;                        // NTILES = 32
    int t = bid & (NTILES - 1);
    int r0 = t * TROWS;

    // zero the padded tile (2080 float4, 512 threads -> 4 full + tail)
    float4* t4 = (float4*)tile;
    float4 z = make_float4(0.f, 0.f, 0.f, 0.f);
    for (int i = threadIdx.x; i < TILE_WORDS / 4; i += 512)
        t4[i] = z;

    int n = (int)min(cnt[bid], (unsigned)CAP);
    __syncthreads();

    const float4* bp = buckets + (size_t)bid * CAP;
    const float* tf = tgt + (size_t)frame * HW;
    double c_img2 = 0.0, c_cross = 0.0;

    for (int i = threadIdx.x; i < n; i += 512) {
        float4 p = bp[i];
        float x = p.x, y = p.y, inten = p.z;     // already clamped at bin time
        float x0f = floorf(x), y0f = floorf(y);
        float fx = x - x0f, fy = y - y0f;
        int x0 = (int)x0f, y0 = (int)y0f;
        int x1 = min(x0 + 1, W - 1);
        int y1 = min(y0 + 1, H - 1);
        int ra = y0 - r0;
        int rb = y1 - r0;
        float w00 = inten * (1.0f - fx) * (1.0f - fy);
        float w01 = inten * fx * (1.0f - fy);
        float w10 = inten * (1.0f - fx) * fy;
        float w11 = inten * fx * fy;

        // gather target pixels (L2/LLC-warm; issued before the LDS atomics)
        float t00 = tf[y0 * W + x0];
        float t01 = tf[y0 * W + x1];
        float t10 = tf[y1 * W + x0];
        float t11 = tf[y1 * W + x1];

        bool ia = (unsigned)ra < (unsigned)TROWS;
        bool ib = (unsigned)rb < (unsigned)TROWS;
        if (ia) {
            lds_add(&tile[ra * TPITCH + x0], w00);
            lds_add(&tile[ra * TPITCH + x1], w01);
        }
        if (ib) {
            lds_add(&tile[rb * TPITCH + x0], w10);
            lds_add(&tile[rb * TPITCH + x1], w11);
        }
        // cross term: count each row-pair only in the tile that owns it
        float cr = 0.0f;
        if (ia) cr += w00 * t00 + w01 * t01;
        if (ib) cr += w10 * t10 + w11 * t11;
        c_cross += (double)cr;
    }
    __syncthreads();

    // Sum(img^2): thread = (row, 16-col slice); reads cols 0..511 only
    {
        int r = threadIdx.x >> 5;                // 16 rows x 32 threads
        int c0 = (threadIdx.x & 31) * 16;
        const float4* rowp = (const float4*)&tile[r * TPITCH + c0];
#pragma unroll
        for (int k = 0; k < 4; ++k) {
            float4 sv = rowp[k];
            c_img2 += (double)(sv.x * sv.x + sv.y * sv.y) +
                      (double)(sv.z * sv.z + sv.w * sv.w);
        }
    }

    double acc = c_img2 - 2.0 * c_cross;
    for (int off = 32; off > 0; off >>= 1)
        acc += __shfl_down(acc, off, 64);
    int lane = threadIdx.x & 63;
    int wave = threadIdx.x >> 6;
    if (lane == 0) sacc[wave] = acc;
    __syncthreads();
    if (threadIdx.x == 0) {
        double s = 0.0;
#pragma unroll
        for (int wv = 0; wv < 8; ++wv) s += sacc[wv];
        ptile[bid] = s;
    }
}

// ---------------------------------------------------------------------------
// Kernel 3: final combine: (Sum tgt^2 + Sum[img^2 - 2 img tgt]) / TOT
// ---------------------------------------------------------------------------
__global__ void __launch_bounds__(512) k_final(const double* __restrict__ pbin,
                                               const double* __restrict__ ptile,
                                               float* __restrict__ out) {
    double acc = 0.0;
    for (int i = threadIdx.x; i < BIN_BLOCKS; i += 512)
        acc += pbin[i];
    for (int i = threadIdx.x; i < NBUCKETS; i += 512)
        acc += ptile[i];
    for (int off = 32; off > 0; off >>= 1)
        acc += __shfl_down(acc, off, 64);
    __shared__ double sacc[8];
    int lane = threadIdx.x & 63;
    int wave = threadIdx.x >> 6;
    if (lane == 0) sacc[wave] = acc;
    __syncthreads();
    if (threadIdx.x == 0) {
        double s = 0.0;
#pragma unroll
        for (int wv = 0; wv < 8; ++wv) s += sacc[wv];
        out[0] = (float)(s / (double)TOT);
    }
}

// ---------------------------------------------------------------------------
extern "C" void kernel_launch(void* const* d_in, const int* in_sizes, int n_in,
                              void* d_out, int out_size, void* d_ws, size_t ws_size,
                              hipStream_t stream) {
    const float* pts = (const float*)d_in[0];     // [B, N, 3]
    const float* tgt = (const float*)d_in[1];     // [B, H, W]
    float* out = (float*)d_out;

    // ws layout: [ cnt 16KB | pbin 8KB | ptile 32KB | pad | buckets 64MiB ]
    unsigned int* cnt = (unsigned int*)d_ws;
    double* pbin  = (double*)((char*)d_ws + 16384);
    double* ptile = (double*)((char*)d_ws + 24576);
    float4* buckets = (float4*)((char*)d_ws + 65536);

    hipMemsetAsync(cnt, 0, NBUCKETS * sizeof(unsigned int), stream);
    k_bin<<<BIN_BLOCKS, 512, 0, stream>>>((const float4*)pts, buckets, cnt,
                                          (const float4*)tgt, pbin);
    k_tile<<<NBUCKETS, 512, 0, stream>>>(buckets, cnt, tgt, ptile);
    k_final<<<1, 512, 0, stream>>>(pbin, ptile, out);
}

// Round 8
// 80.808 us; speedup vs baseline: 1.5835x; 1.2938x over previous
//
#include <hip/hip_runtime.h>

// Problem constants (match reference)
constexpr int B = 128;
constexpr int N = 16384;
constexpr int H = 512;
constexpr int W = 512;
constexpr int HW = H * W;                        // 262144
constexpr long long TOT = (long long)B * HW;     // 33554432 pixels

constexpr int TROWS = 16;                        // rows per tile
constexpr int NTILES = H / TROWS;                // 32 tiles per frame
constexpr int NBUCKETS = B * NTILES;             // 4096
constexpr int CAP = 1024;                        // slots per bucket (mean ~545)
constexpr int NGROUPS = B * N / 4;               // 524288 groups of 4 points
constexpr int BIN_BLOCKS = NGROUPS / 512;        // 1024
constexpr int TPITCH = 520;                      // padded pitch (bank spread)
constexpr int TILE_WORDS = TROWS * TPITCH;       // 8320 floats = 33280 B

__device__ __forceinline__ void lds_add(float* p, float v) {
    __hip_atomic_fetch_add(p, v, __ATOMIC_RELAXED, __HIP_MEMORY_SCOPE_WORKGROUP);
}

// keep-alive pin: forces the load to materialize HERE (can't sink past)
__device__ __forceinline__ void pin(float4& v) {
    asm volatile("" : "+v"(v.x), "+v"(v.y), "+v"(v.z), "+v"(v.w));
}

// ---------------------------------------------------------------------------
// Kernel 0: zero the 4096 bucket counters (replaces hipMemsetAsync node)
// ---------------------------------------------------------------------------
__global__ void __launch_bounds__(512) k_zero(unsigned int* __restrict__ cnt) {
    cnt[blockIdx.x * 512 + threadIdx.x] = 0u;
}

// ---------------------------------------------------------------------------
// Kernel 1: bin points by (frame, row-tile), per-block LDS slot aggregation.
// (r4/r5 version, measured ~5us)
// ---------------------------------------------------------------------------
__global__ void __launch_bounds__(512) k_bin(const float4* __restrict__ pts,
                                             float4* __restrict__ buckets,
                                             unsigned int* __restrict__ cnt) {
    __shared__ unsigned int lcnt[NTILES];
    __shared__ unsigned int lbase[NTILES];

    int tid = blockIdx.x * 512 + threadIdx.x;    // one group of 4 points
    int frame = tid >> 12;                       // 4096 groups per frame
    int fb = frame * NTILES;

    if (threadIdx.x < NTILES) lcnt[threadIdx.x] = 0;
    __syncthreads();

    float4 a = pts[tid * 3 + 0];   // x0 y0 i0 x1
    float4 b = pts[tid * 3 + 1];   // y1 i1 x2 y2
    float4 c = pts[tid * 3 + 2];   // i2 x3 y3 i3

    float xs[4] = {a.x, a.w, b.z, c.y};
    float ys[4] = {a.y, b.x, b.w, c.z};
    float is[4] = {a.z, b.y, c.x, c.w};

    int tb0[4], sl0[4], tb1[4], sl1[4];
#pragma unroll
    for (int k = 0; k < 4; ++k) {
        float x = fminf(fmaxf(xs[k], 0.0f), (float)(W - 1));
        float y = fminf(fmaxf(ys[k], 0.0f), (float)(H - 1));
        xs[k] = x; ys[k] = y;
        int y0 = (int)floorf(y);
        int y1 = min(y0 + 1, H - 1);
        int t0 = y0 >> 4;                         // TROWS = 16
        int t1 = y1 >> 4;
        tb0[k] = t0;
        sl0[k] = (int)atomicAdd(&lcnt[t0], 1u);
        if (t1 != t0) {
            tb1[k] = t1;
            sl1[k] = (int)atomicAdd(&lcnt[t1], 1u);
        } else {
            tb1[k] = -1; sl1[k] = 0;
        }
    }
    __syncthreads();

    if (threadIdx.x < NTILES)
        lbase[threadIdx.x] = atomicAdd(&cnt[fb + threadIdx.x], lcnt[threadIdx.x]);
    __syncthreads();

#pragma unroll
    for (int k = 0; k < 4; ++k) {
        float4 rec = make_float4(xs[k], ys[k], is[k], 0.0f);
        unsigned s0 = lbase[tb0[k]] + (unsigned)sl0[k];
        if (s0 < (unsigned)CAP)
            buckets[(size_t)(fb + tb0[k]) * CAP + s0] = rec;
        if (tb1[k] >= 0) {
            unsigned s1 = lbase[tb1[k]] + (unsigned)sl1[k];
            if (s1 < (unsigned)CAP)
                buckets[(size_t)(fb + tb1[k]) * CAP + s1] = rec;
        }
    }
}

// ---------------------------------------------------------------------------
// Kernel 2: per-(frame,tile) block. All 7 global loads pinned up front
// (latency hides under zero-phase + other blocks), guarded 2-slot splat via
// ds_add_f32 into bank-padded tile, then (img - tgt)^2 from registers.
// ---------------------------------------------------------------------------
__device__ __forceinline__ void splat(float4 p, float* __restrict__ tile, int r0) {
    float x = p.x, y = p.y, inten = p.z;         // clamped at bin time
    float x0f = floorf(x), y0f = floorf(y);
    float fx = x - x0f, fy = y - y0f;
    int x0 = (int)x0f, y0 = (int)y0f;
    int x1 = min(x0 + 1, W - 1);
    int y1 = min(y0 + 1, H - 1);
    int ra = y0 - r0;
    int rb = y1 - r0;
    float w00 = inten * (1.0f - fx) * (1.0f - fy);
    float w01 = inten * fx * (1.0f - fy);
    float w10 = inten * (1.0f - fx) * fy;
    float w11 = inten * fx * fy;
    if ((unsigned)ra < (unsigned)TROWS) {
        lds_add(&tile[ra * TPITCH + x0], w00);
        lds_add(&tile[ra * TPITCH + x1], w01);
    }
    if ((unsigned)rb < (unsigned)TROWS) {
        lds_add(&tile[rb * TPITCH + x0], w10);
        lds_add(&tile[rb * TPITCH + x1], w11);
    }
}

__global__ void __launch_bounds__(512) k_tile(const float4* __restrict__ buckets,
                                              const unsigned int* __restrict__ cnt,
                                              const float* __restrict__ tgt,
                                              double* __restrict__ ptile) {
    __shared__ __align__(16) float tile[TILE_WORDS];   // 33280 B
    __shared__ double sacc[8];
    int bid = blockIdx.x;
    int frame = bid >> 5;                        // NTILES = 32
    int t = bid & (NTILES - 1);
    int r0 = t * TROWS;
    int tid = threadIdx.x;

    // ---- issue ALL global loads now; pin so they can't sink ----
    const float4* bp = buckets + (size_t)bid * CAP;
    float4 p0 = bp[tid];                         // slots >= n are stale/garbage,
    float4 p1 = bp[tid + 512];                   // discarded by the n-guard below
    const float4* tg = (const float4*)(tgt + (size_t)frame * HW + (size_t)r0 * W);
    float4 tv0 = tg[tid];
    float4 tv1 = tg[tid + 512];
    float4 tv2 = tg[tid + 1024];
    float4 tv3 = tg[tid + 1536];
    int n = (int)min(cnt[bid], (unsigned)CAP);
    pin(p0); pin(p1); pin(tv0); pin(tv1); pin(tv2); pin(tv3);

    // ---- zero padded tile while loads fly ----
    float4* t4 = (float4*)tile;
    float4 z = make_float4(0.f, 0.f, 0.f, 0.f);
    for (int i = tid; i < TILE_WORDS / 4; i += 512)
        t4[i] = z;
    __syncthreads();                             // also drains vmcnt

    // ---- guarded splat: exactly <=2 points per thread, zero mem waits ----
    if (tid < n)       splat(p0, tile, r0);
    if (tid + 512 < n) splat(p1, tile, r0);
    __syncthreads();

    // ---- (img - tgt)^2, f32 per-thread accumulate, targets in registers ----
    float facc = 0.0f;
#pragma unroll
    for (int k = 0; k < 4; ++k) {
        int g = tid + k * 512;                   // float4 index in 512-col space
        int r = g >> 7;                          // row (128 float4 per row)
        int c = (g & 127) << 2;                  // col in floats
        float4 sv = *(const float4*)&tile[r * TPITCH + c];
        float4 tv = (k == 0) ? tv0 : (k == 1) ? tv1 : (k == 2) ? tv2 : tv3;
        float d0 = sv.x - tv.x, d1 = sv.y - tv.y;
        float d2 = sv.z - tv.z, d3 = sv.w - tv.w;
        facc += d0 * d0 + d1 * d1 + d2 * d2 + d3 * d3;
    }

    double acc = (double)facc;
    for (int off = 32; off > 0; off >>= 1)
        acc += __shfl_down(acc, off, 64);
    int lane = tid & 63;
    int wave = tid >> 6;
    if (lane == 0) sacc[wave] = acc;
    __syncthreads();
    if (tid == 0) {
        double s = 0.0;
#pragma unroll
        for (int wv = 0; wv < 8; ++wv) s += sacc[wv];
        ptile[bid] = s;
    }
}

// ---------------------------------------------------------------------------
// Kernel 3: final reduce of NBUCKETS partials -> mean -> d_out[0]
// ---------------------------------------------------------------------------
__global__ void __launch_bounds__(512) k_final(const double* __restrict__ ptile,
                                               float* __restrict__ out) {
    double acc = 0.0;
    for (int i = threadIdx.x; i < NBUCKETS; i += 512)
        acc += ptile[i];
    for (int off = 32; off > 0; off >>= 1)
        acc += __shfl_down(acc, off, 64);
    __shared__ double sacc[8];
    int lane = threadIdx.x & 63;
    int wave = threadIdx.x >> 6;
    if (lane == 0) sacc[wave] = acc;
    __syncthreads();
    if (threadIdx.x == 0) {
        double s = 0.0;
#pragma unroll
        for (int wv = 0; wv < 8; ++wv) s += sacc[wv];
        out[0] = (float)(s / (double)TOT);
    }
}

// ---------------------------------------------------------------------------
extern "C" void kernel_launch(void* const* d_in, const int* in_sizes, int n_in,
                              void* d_out, int out_size, void* d_ws, size_t ws_size,
                              hipStream_t stream) {
    const float* pts = (const float*)d_in[0];     // [B, N, 3]
    const float* tgt = (const float*)d_in[1];     // [B, H, W]
    float* out = (float*)d_out;

    // ws layout: [ cnt 16KB | ptile 32KB | pad to 64KB | buckets 64MiB ]
    unsigned int* cnt = (unsigned int*)d_ws;
    double* ptile = (double*)((char*)d_ws + 16384);
    float4* buckets = (float4*)((char*)d_ws + 65536);

    k_zero<<<NBUCKETS / 512, 512, 0, stream>>>(cnt);
    k_bin<<<BIN_BLOCKS, 512, 0, stream>>>((const float4*)pts, buckets, cnt);
    k_tile<<<NBUCKETS, 512, 0, stream>>>(buckets, cnt, tgt, ptile);
    k_final<<<1, 512, 0, stream>>>(ptile, out);
}